// Round 11
// baseline (330.647 us; speedup 1.0000x reference)
//
#include <hip/hip_runtime.h>

// GCN encoder: h1 = relu(x@fcW+fcb); h2 = relu(gcn(h1,W1,b1)); out = relu(gcn(h2,W2,b2))
// gcn(x,W,b)[i] = sum_{e:dst=i} (x@W)[src_e]*norm_e + (x@W)[i]*dinv[i]^2 + b
// Aggregation: dst-sorted CSR on device; per-node float4 gather.
// GEMM: split-bf16 MFMA, pre-converted hi/lo planes (round 10), plus:
//  - XCD-bijective block swizzle (1-D grid): each XCD gets contiguous
//    m-panels so A re-reads hit its own L2 (round 10: A re-fetched from HBM
//    once per column block -> FETCH 108 MB/GEMM).
//  - register prefetch of tile k+1 issued BEFORE computing tile k: global
//    latency hides under MFMA instead of serializing each K-step.
// No min-waves in __launch_bounds__ (rounds 5/6: hipcc spills to meet it).

namespace {
constexpr int NN = 20000;
constexpr int NE = 320000;
constexpr int IN_FT = 256, HID1 = 400, HID2 = 200, OUT_FT = 128;
constexpr int K1P = 416;  // HID1 padded to 32 (13 tiles)
constexpr int K2P = 224;  // HID2 padded to 32 (7 tiles)
using short8v = __attribute__((ext_vector_type(8))) short;
using f32x4 = __attribute__((ext_vector_type(4))) float;
}

__device__ __forceinline__ unsigned short f2bf(float f) {
  unsigned int u = __float_as_uint(f);
  u += 0x7FFFu + ((u >> 16) & 1u);  // round-to-nearest-even
  return (unsigned short)(u >> 16);
}
__device__ __forceinline__ float bf2f(unsigned short h) {
  return __uint_as_float(((unsigned int)h) << 16);
}

// deg (weighted, +1 self loop) and integer count per dst in one pass
__global__ __launch_bounds__(256) void deg_count_kernel(const int* __restrict__ dst,
                                                        const float* __restrict__ ew,
                                                        float* __restrict__ deg,
                                                        int* __restrict__ cnt) {
  int tid = blockIdx.x * 256 + threadIdx.x;
  if (tid < NE) {
    int d = dst[tid];
    unsafeAtomicAdd(&deg[d], ew[tid]);
    atomicAdd(&cnt[d], 1);
  } else if (tid < NE + NN) {
    unsafeAtomicAdd(&deg[tid - NE], 1.0f);  // self-loop weight 1
  }
}

__global__ __launch_bounds__(256) void dinv_kernel(float* __restrict__ deg) {
  int i = blockIdx.x * 256 + threadIdx.x;
  if (i < NN) {
    float d = deg[i];
    deg[i] = d > 0.f ? rsqrtf(d) : 0.f;  // in place: deg -> dinv
  }
}

// single-block exclusive scan: count[NN] -> rowptr[NN+1]; count becomes fill cursor
__global__ __launch_bounds__(1024) void scan_kernel(int* __restrict__ count,
                                                    int* __restrict__ rowptr) {
  constexpr int CHUNK = (NN + 1023) / 1024;  // 20
  __shared__ int partial[1024];
  const int t = threadIdx.x;
  const int base = t * CHUNK;
  int s = 0;
#pragma unroll
  for (int i = 0; i < CHUNK; ++i) {
    int idx = base + i;
    if (idx < NN) s += count[idx];
  }
  partial[t] = s;
  __syncthreads();
  for (int off = 1; off < 1024; off <<= 1) {
    int v = 0;
    if (t >= off) v = partial[t - off];
    __syncthreads();
    if (t >= off) partial[t] += v;
    __syncthreads();
  }
  int excl = partial[t] - s;
#pragma unroll
  for (int i = 0; i < CHUNK; ++i) {
    int idx = base + i;
    if (idx < NN) {
      int c = count[idx];
      rowptr[idx] = excl;
      count[idx] = excl;  // becomes the scatter fill cursor
      excl += c;
    }
  }
  if (t == 1023) rowptr[NN] = partial[1023];
}

// scatter edges into dst-sorted order, computing norm inline
__global__ __launch_bounds__(256) void scatter_kernel(const int* __restrict__ src,
                                                      const int* __restrict__ dst,
                                                      const float* __restrict__ ew,
                                                      const float* __restrict__ dinv,
                                                      int* __restrict__ fill,
                                                      int* __restrict__ srcS,
                                                      float* __restrict__ wS) {
  int e = blockIdx.x * 256 + threadIdx.x;
  if (e >= NE) return;
  int s = src[e], d = dst[e];
  int pos = atomicAdd(&fill[d], 1);
  srcS[pos] = s;
  wS[pos] = dinv[s] * ew[e] * dinv[d];
}

// split fp32 array into bf16 hi/lo planes, 8 elems/thread (n % 8 == 0)
__global__ __launch_bounds__(256) void split_kernel(const float* __restrict__ in,
                                                    unsigned short* __restrict__ hi,
                                                    unsigned short* __restrict__ lo,
                                                    int n8) {
  int i = blockIdx.x * 256 + threadIdx.x;
  if (i >= n8) return;
  const float4 v0 = reinterpret_cast<const float4*>(in)[i * 2];
  const float4 v1 = reinterpret_cast<const float4*>(in)[i * 2 + 1];
  const float v[8] = {v0.x, v0.y, v0.z, v0.w, v1.x, v1.y, v1.z, v1.w};
  short8v h, l;
#pragma unroll
  for (int j = 0; j < 8; ++j) {
    unsigned short hh = f2bf(v[j]);
    h[j] = (short)hh;
    l[j] = (short)f2bf(v[j] - bf2f(hh));
  }
  reinterpret_cast<short8v*>(hi)[i] = h;
  reinterpret_cast<short8v*>(lo)[i] = l;
}

// W[K,N] -> transposed bf16 hi/lo planes [N][Kpad], zero-padded k>=K
__global__ __launch_bounds__(256) void wtrans_kernel(const float* __restrict__ W,
                                                     unsigned short* __restrict__ th,
                                                     unsigned short* __restrict__ tl,
                                                     int K, int N, int Kpad) {
  int idx = blockIdx.x * 256 + threadIdx.x;
  if (idx >= N * Kpad) return;
  int n = idx / Kpad, k = idx - n * Kpad;
  float v = (k < K) ? W[(size_t)k * N + n] : 0.f;
  unsigned short h = f2bf(v);
  th[idx] = h;
  tl[idx] = f2bf(v - bf2f(h));
}

// C[M,N] = A[M,KA] @ B[KA,N] from pre-split planes.
// Ah/Al: [M][KA] bf16 planes. BTh/BTl: [N][KB] transposed zero-padded planes.
// 1-D grid, XCD-bijective swizzle; register prefetch of next tile.
// 128x64 tile, BK=32, 4 waves (2x2), wave = 4x2 16x16 frags.
template <bool BIAS, bool RELU, bool SPLIT>
__global__ __launch_bounds__(256) void gemm_pre_kernel(
    const unsigned short* __restrict__ Ah, const unsigned short* __restrict__ Al,
    const unsigned short* __restrict__ BTh, const unsigned short* __restrict__ BTl,
    const float* __restrict__ bias, float* __restrict__ Cf,
    unsigned short* __restrict__ Ch, unsigned short* __restrict__ Cl,
    int M, int KA, int KB, int N, int nBx) {
  __shared__ unsigned short Ash[128][40];
  __shared__ unsigned short Asl[128][40];
  __shared__ unsigned short Bsh[64][40];
  __shared__ unsigned short Bsl[64][40];
  // XCD-bijective swizzle (m204): XCD x owns a contiguous range of logical
  // block ids -> consecutive m-panels stay in one XCD's L2.
  const int nwg = gridDim.x;
  const int q = nwg >> 3, r = nwg & 7;
  const int xcd = blockIdx.x & 7, bi = blockIdx.x >> 3;
  const int swz = (xcd < r ? xcd * (q + 1) : r * (q + 1) + (xcd - r) * q) + bi;
  const int by = swz / nBx, bx = swz - by * nBx;
  const int m0 = by * 128, n0 = bx * 64;

  const int tid = threadIdx.x;
  const int lane = tid & 63;
  const int wid = tid >> 6;
  const int wm = wid >> 1, wn = wid & 1;  // 2x2 wave grid
  const int ar = tid >> 1, ako = (tid & 1) * 16;  // A staging: row, k-offset
  const int arow = m0 + ar;
  const int bn = tid >> 2, bko = (tid & 3) * 8;   // B staging: n-row, k-offset
  const int brow = n0 + bn;
  const int l15 = lane & 15, kg = lane >> 4;
  const short8v zv = {0, 0, 0, 0, 0, 0, 0, 0};

  f32x4 acc[4][2];
#pragma unroll
  for (int i = 0; i < 4; ++i)
#pragma unroll
    for (int j = 0; j < 2; ++j)
#pragma unroll
      for (int c = 0; c < 4; ++c) acc[i][j][c] = 0.f;

  // prefetch registers (tile in flight)
  short8v pa0h = zv, pa1h = zv, pa0l = zv, pa1l = zv, pbh = zv, pbl = zv;
  auto gload = [&](int k0) {
    if (arow < M) {
      const size_t off = (size_t)arow * KA + k0 + ako;
      pa0h = *reinterpret_cast<const short8v*>(Ah + off);
      pa1h = *reinterpret_cast<const short8v*>(Ah + off + 8);
      pa0l = *reinterpret_cast<const short8v*>(Al + off);
      pa1l = *reinterpret_cast<const short8v*>(Al + off + 8);
    } else {
      pa0h = pa1h = pa0l = pa1l = zv;
    }
    if (brow < N) {
      const size_t off = (size_t)brow * KB + k0 + bko;
      pbh = *reinterpret_cast<const short8v*>(BTh + off);
      pbl = *reinterpret_cast<const short8v*>(BTl + off);
    } else {
      pbh = pbl = zv;
    }
  };
  auto sstore = [&]() {
    *reinterpret_cast<short8v*>(&Ash[ar][ako]) = pa0h;
    *reinterpret_cast<short8v*>(&Ash[ar][ako + 8]) = pa1h;
    *reinterpret_cast<short8v*>(&Asl[ar][ako]) = pa0l;
    *reinterpret_cast<short8v*>(&Asl[ar][ako + 8]) = pa1l;
    *reinterpret_cast<short8v*>(&Bsh[bn][bko]) = pbh;
    *reinterpret_cast<short8v*>(&Bsl[bn][bko]) = pbl;
  };

  gload(0);
  for (int k0 = 0; k0 < KB; k0 += 32) {
    sstore();
    __syncthreads();
    if (k0 + 32 < KB) gload(k0 + 32);  // in flight under this tile's compute
    short8v afh[4], afl[4], bfh[2], bfl[2];
#pragma unroll
    for (int mf = 0; mf < 4; ++mf) {
      const int rr = wm * 64 + mf * 16 + l15;
      afh[mf] = *reinterpret_cast<const short8v*>(&Ash[rr][kg * 8]);
      afl[mf] = *reinterpret_cast<const short8v*>(&Asl[rr][kg * 8]);
    }
#pragma unroll
    for (int nf = 0; nf < 2; ++nf) {
      const int cc = wn * 32 + nf * 16 + l15;
      bfh[nf] = *reinterpret_cast<const short8v*>(&Bsh[cc][kg * 8]);
      bfl[nf] = *reinterpret_cast<const short8v*>(&Bsl[cc][kg * 8]);
    }
#pragma unroll
    for (int mf = 0; mf < 4; ++mf)
#pragma unroll
      for (int nf = 0; nf < 2; ++nf) {
        acc[mf][nf] = __builtin_amdgcn_mfma_f32_16x16x32_bf16(afh[mf], bfh[nf], acc[mf][nf], 0, 0, 0);
        acc[mf][nf] = __builtin_amdgcn_mfma_f32_16x16x32_bf16(afh[mf], bfl[nf], acc[mf][nf], 0, 0, 0);
        acc[mf][nf] = __builtin_amdgcn_mfma_f32_16x16x32_bf16(afl[mf], bfh[nf], acc[mf][nf], 0, 0, 0);
      }
    __syncthreads();
  }

  // epilogue: C/D layout col=lane&15, row=(lane>>4)*4+reg (guide §3, m89/m91)
#pragma unroll
  for (int nf = 0; nf < 2; ++nf) {
    const int col = n0 + wn * 32 + nf * 16 + l15;
    if (col >= N) continue;
    float bb = 0.f;
    if (BIAS) bb = bias[col];
#pragma unroll
    for (int mf = 0; mf < 4; ++mf) {
      const int rbase = m0 + wm * 64 + mf * 16 + kg * 4;
#pragma unroll
      for (int i = 0; i < 4; ++i) {
        const int row = rbase + i;
        if (row >= M) continue;
        float v = acc[mf][nf][i];
        if (BIAS) v += bb;
        if (RELU) v = fmaxf(v, 0.f);
        if (SPLIT) {
          unsigned short h = f2bf(v);
          Ch[(size_t)row * N + col] = h;
          Cl[(size_t)row * N + col] = f2bf(v - bf2f(h));
        } else {
          Cf[(size_t)row * N + col] = v;
        }
      }
    }
  }
}

// Fused gather-aggregate + self-loop + bias + relu.
// NPW nodes/wave; F/4 lanes per node, ONE float4 per edge per lane.
// SPLIT: write bf16 hi/lo planes (feeds next GEMM); else fp32.
template <int F, int NPW, bool SPLIT>
__global__ __launch_bounds__(256) void agg_gather_kernel(const int* __restrict__ rowptr,
                                                         const int* __restrict__ srcS,
                                                         const float* __restrict__ wS,
                                                         const float* __restrict__ t,
                                                         const float* __restrict__ dinv,
                                                         const float* __restrict__ bias,
                                                         float* __restrict__ out,
                                                         unsigned short* __restrict__ oh,
                                                         unsigned short* __restrict__ ol) {
  constexpr int LPN = F / 4;  // float4 lanes per node
  const int wv = threadIdx.x >> 6;
  const int lane = threadIdx.x & 63;
  const int sub = (NPW == 2) ? (lane >> 5) : 0;
  const int l = (NPW == 2) ? (lane & 31) : lane;
  const int node = blockIdx.x * (4 * NPW) + wv * NPW + sub;
  if (node >= NN || l >= LPN) return;  // no barriers/shuffles below: safe exit
  const int beg = rowptr[node], end = rowptr[node + 1];
  const size_t fo = (size_t)l * 4;
  float4 acc0 = make_float4(0.f, 0.f, 0.f, 0.f);
  float4 acc1 = make_float4(0.f, 0.f, 0.f, 0.f);
  int j = beg;
  for (; j + 1 < end; j += 2) {  // 2-way unroll: independent load->FMA chains
    const int s0 = srcS[j], s1 = srcS[j + 1];
    const float w0 = wS[j], w1 = wS[j + 1];
    const float4 v0 = *reinterpret_cast<const float4*>(t + (size_t)s0 * F + fo);
    const float4 v1 = *reinterpret_cast<const float4*>(t + (size_t)s1 * F + fo);
    acc0.x = fmaf(v0.x, w0, acc0.x); acc0.y = fmaf(v0.y, w0, acc0.y);
    acc0.z = fmaf(v0.z, w0, acc0.z); acc0.w = fmaf(v0.w, w0, acc0.w);
    acc1.x = fmaf(v1.x, w1, acc1.x); acc1.y = fmaf(v1.y, w1, acc1.y);
    acc1.z = fmaf(v1.z, w1, acc1.z); acc1.w = fmaf(v1.w, w1, acc1.w);
  }
  if (j < end) {
    const int s0 = srcS[j];
    const float w0 = wS[j];
    const float4 v0 = *reinterpret_cast<const float4*>(t + (size_t)s0 * F + fo);
    acc0.x = fmaf(v0.x, w0, acc0.x); acc0.y = fmaf(v0.y, w0, acc0.y);
    acc0.z = fmaf(v0.z, w0, acc0.z); acc0.w = fmaf(v0.w, w0, acc0.w);
  }
  const float di = dinv[node];
  const float sw = di * di;
  const float4 tv = *reinterpret_cast<const float4*>(t + (size_t)node * F + fo);
  const float4 bb = *reinterpret_cast<const float4*>(bias + fo);
  float4 o;
  o.x = fmaxf(fmaf(tv.x, sw, acc0.x + acc1.x) + bb.x, 0.f);
  o.y = fmaxf(fmaf(tv.y, sw, acc0.y + acc1.y) + bb.y, 0.f);
  o.z = fmaxf(fmaf(tv.z, sw, acc0.z + acc1.z) + bb.z, 0.f);
  o.w = fmaxf(fmaf(tv.w, sw, acc0.w + acc1.w) + bb.w, 0.f);
  if (SPLIT) {
    ushort4 hv, lv;
    hv.x = f2bf(o.x); lv.x = f2bf(o.x - bf2f(hv.x));
    hv.y = f2bf(o.y); lv.y = f2bf(o.y - bf2f(hv.y));
    hv.z = f2bf(o.z); lv.z = f2bf(o.z - bf2f(hv.z));
    hv.w = f2bf(o.w); lv.w = f2bf(o.w - bf2f(hv.w));
    *reinterpret_cast<ushort4*>(oh + (size_t)node * F + fo) = hv;
    *reinterpret_cast<ushort4*>(ol + (size_t)node * F + fo) = lv;
  } else {
    *reinterpret_cast<float4*>(out + (size_t)node * F + fo) = o;
  }
}

extern "C" void kernel_launch(void* const* d_in, const int* in_sizes, int n_in,
                              void* d_out, int out_size, void* d_ws, size_t ws_size,
                              hipStream_t stream) {
  const float* x = (const float*)d_in[0];
  const int* ei = (const int*)d_in[1];  // int32 per harness conversion
  const float* ea = (const float*)d_in[2];
  const float* fcW = (const float*)d_in[3];
  const float* fcb = (const float*)d_in[4];
  const float* W1 = (const float*)d_in[5];
  const float* b1 = (const float*)d_in[6];
  const float* W2 = (const float*)d_in[7];
  const float* b2 = (const float*)d_in[8];
  const int* srcIdx = ei;       // edge_index[0]
  const int* dstIdx = ei + NE;  // edge_index[1]

  char* ws = (char*)d_ws;
  constexpr size_t KB_ = 1u << 10;
  typedef unsigned short us;
  float* dinv = (float*)(ws);                  // 80 KB
  int* rowptr = (int*)(ws + 128 * KB_);        // 80 KB
  int* cnt = (int*)(ws + 256 * KB_);           // 80 KB (count -> fill cursor)
  int* srcS = (int*)(ws + 384 * KB_);          // 1.28 MB
  float* wS = (float*)(ws + 1792 * KB_);       // 1.28 MB
  us* fcWTh = (us*)(ws + 3200 * KB_);          // 400x256 bf16 = 200 KB
  us* fcWTl = (us*)(ws + 3456 * KB_);
  us* W1Th = (us*)(ws + 3712 * KB_);           // 200x416 = 163 KB
  us* W1Tl = (us*)(ws + 3968 * KB_);
  us* W2Th = (us*)(ws + 4224 * KB_);           // 128x224 = 56 KB
  us* W2Tl = (us*)(ws + 4352 * KB_);
  us* xh = (us*)(ws + 4608 * KB_);             // 20000x256 = 9.77 MB
  us* xl = (us*)(ws + 14848 * KB_);            // ends ~24.3 MB
  float* t1 = (float*)(ws + 4608 * KB_);       // 15.26 MB (x dead) -> also t2
  us* h1h = (us*)(ws + 25600 * KB_);           // 20000x400 = 15.26 MB
  us* h1l = (us*)(ws + 41472 * KB_);           // ends ~55.8 MB (peak)
  us* h2h = (us*)(ws + 25600 * KB_);           // 7.63 MB (h1 dead)
  us* h2l = (us*)(ws + 33664 * KB_);
  float* t2 = (float*)(ws + 4608 * KB_);       // 9.77 MB (t1 dead)

  // --- normalization + CSR (shared by both GCN layers) ---
  hipMemsetAsync(dinv, 0, NN * sizeof(float), stream);
  hipMemsetAsync(cnt, 0, NN * sizeof(int), stream);
  deg_count_kernel<<<(NE + NN + 255) / 256, 256, 0, stream>>>(dstIdx, ea, dinv, cnt);
  dinv_kernel<<<(NN + 255) / 256, 256, 0, stream>>>(dinv);
  scan_kernel<<<1, 1024, 0, stream>>>(cnt, rowptr);
  scatter_kernel<<<(NE + 255) / 256, 256, 0, stream>>>(srcIdx, dstIdx, ea, dinv, cnt, srcS, wS);

  // --- one-time operand prep: split x, transpose+split weights ---
  split_kernel<<<(NN * IN_FT / 8 + 255) / 256, 256, 0, stream>>>(x, xh, xl, NN * IN_FT / 8);
  wtrans_kernel<<<(HID1 * IN_FT + 255) / 256, 256, 0, stream>>>(fcW, fcWTh, fcWTl, IN_FT, HID1, IN_FT);
  wtrans_kernel<<<(HID2 * K1P + 255) / 256, 256, 0, stream>>>(W1, W1Th, W1Tl, HID1, HID2, K1P);
  wtrans_kernel<<<(OUT_FT * K2P + 255) / 256, 256, 0, stream>>>(W2, W2Th, W2Tl, HID2, OUT_FT, K2P);

  const int MBLK = (NN + 127) / 128;  // 157 row blocks

  // --- h1 = relu(x @ fcW + fcb), written as bf16 hi/lo planes ---
  gemm_pre_kernel<true, true, true><<<7 * MBLK, 256, 0, stream>>>(
      xh, xl, fcWTh, fcWTl, fcb, nullptr, h1h, h1l, NN, IN_FT, IN_FT, HID1, 7);

  // --- layer 1: t1 = h1 @ W1 (fp32); h2 = relu(agg(t1)+..), split planes ---
  gemm_pre_kernel<false, false, false><<<4 * MBLK, 256, 0, stream>>>(
      h1h, h1l, W1Th, W1Tl, nullptr, t1, nullptr, nullptr, NN, HID1, K1P, HID2, 4);
  agg_gather_kernel<HID2, 1, true><<<(NN + 3) / 4, 256, 0, stream>>>(
      rowptr, srcS, wS, t1, dinv, b1, nullptr, h2h, h2l);

  // --- layer 2: t2 = h2 @ W2 (fp32); out = relu(agg(t2)+..) fp32 ---
  gemm_pre_kernel<false, false, false><<<2 * MBLK, 256, 0, stream>>>(
      h2h, h2l, W2Th, W2Tl, nullptr, t2, nullptr, nullptr, NN, HID2, K2P, OUT_FT, 2);
  agg_gather_kernel<OUT_FT, 2, false><<<(NN + 7) / 8, 256, 0, stream>>>(
      rowptr, srcS, wS, t2, dinv, b2, (float*)d_out, nullptr, nullptr);
}

// Round 12
// 266.103 us; speedup vs baseline: 1.2426x; 1.2426x over previous
//
#include <hip/hip_runtime.h>

// GCN encoder: h1 = relu(x@fcW+fcb); h2 = relu(gcn(h1,W1,b1)); out = relu(gcn(h2,W2,b2))
// gcn(x,W,b)[i] = sum_{e:dst=i} (x@W)[src_e]*norm_e + (x@W)[i]*dinv[i]^2 + b
// Aggregation: dst-sorted CSR on device; per-node float4 gather.
// GEMM: split-bf16 MFMA, pre-converted hi/lo planes (round 10). 64x64 tile,
// BK=32, 4 waves (2x2), wave = 2x2 16x16 frags. Rationale: round 10's 128x64
// tile gave only 4.3 blocks/CU (occupancy 28-33%) and the K-loop is
// latency-bound -- smaller tile doubles the grid (8.5 blocks/CU for fc) and
// cuts LDS to 20.5 KB so ~6 independent blocks/CU hide the per-iteration
// latency. Round 11's XCD swizzle + prefetch reorder reverted (regression;
// FETCH was L3-served, not the bottleneck).
// No min-waves in __launch_bounds__ (rounds 5/6: hipcc spills to meet it).

namespace {
constexpr int NN = 20000;
constexpr int NE = 320000;
constexpr int IN_FT = 256, HID1 = 400, HID2 = 200, OUT_FT = 128;
constexpr int K1P = 416;  // HID1 padded to 32 (13 tiles)
constexpr int K2P = 224;  // HID2 padded to 32 (7 tiles)
using short8v = __attribute__((ext_vector_type(8))) short;
using f32x4 = __attribute__((ext_vector_type(4))) float;
}

__device__ __forceinline__ unsigned short f2bf(float f) {
  unsigned int u = __float_as_uint(f);
  u += 0x7FFFu + ((u >> 16) & 1u);  // round-to-nearest-even
  return (unsigned short)(u >> 16);
}
__device__ __forceinline__ float bf2f(unsigned short h) {
  return __uint_as_float(((unsigned int)h) << 16);
}

// deg (weighted, +1 self loop) and integer count per dst in one pass
__global__ __launch_bounds__(256) void deg_count_kernel(const int* __restrict__ dst,
                                                        const float* __restrict__ ew,
                                                        float* __restrict__ deg,
                                                        int* __restrict__ cnt) {
  int tid = blockIdx.x * 256 + threadIdx.x;
  if (tid < NE) {
    int d = dst[tid];
    unsafeAtomicAdd(&deg[d], ew[tid]);
    atomicAdd(&cnt[d], 1);
  } else if (tid < NE + NN) {
    unsafeAtomicAdd(&deg[tid - NE], 1.0f);  // self-loop weight 1
  }
}

__global__ __launch_bounds__(256) void dinv_kernel(float* __restrict__ deg) {
  int i = blockIdx.x * 256 + threadIdx.x;
  if (i < NN) {
    float d = deg[i];
    deg[i] = d > 0.f ? rsqrtf(d) : 0.f;  // in place: deg -> dinv
  }
}

// single-block exclusive scan: count[NN] -> rowptr[NN+1]; count becomes fill cursor
__global__ __launch_bounds__(1024) void scan_kernel(int* __restrict__ count,
                                                    int* __restrict__ rowptr) {
  constexpr int CHUNK = (NN + 1023) / 1024;  // 20
  __shared__ int partial[1024];
  const int t = threadIdx.x;
  const int base = t * CHUNK;
  int s = 0;
#pragma unroll
  for (int i = 0; i < CHUNK; ++i) {
    int idx = base + i;
    if (idx < NN) s += count[idx];
  }
  partial[t] = s;
  __syncthreads();
  for (int off = 1; off < 1024; off <<= 1) {
    int v = 0;
    if (t >= off) v = partial[t - off];
    __syncthreads();
    if (t >= off) partial[t] += v;
    __syncthreads();
  }
  int excl = partial[t] - s;
#pragma unroll
  for (int i = 0; i < CHUNK; ++i) {
    int idx = base + i;
    if (idx < NN) {
      int c = count[idx];
      rowptr[idx] = excl;
      count[idx] = excl;  // becomes the scatter fill cursor
      excl += c;
    }
  }
  if (t == 1023) rowptr[NN] = partial[1023];
}

// scatter edges into dst-sorted order, computing norm inline
__global__ __launch_bounds__(256) void scatter_kernel(const int* __restrict__ src,
                                                      const int* __restrict__ dst,
                                                      const float* __restrict__ ew,
                                                      const float* __restrict__ dinv,
                                                      int* __restrict__ fill,
                                                      int* __restrict__ srcS,
                                                      float* __restrict__ wS) {
  int e = blockIdx.x * 256 + threadIdx.x;
  if (e >= NE) return;
  int s = src[e], d = dst[e];
  int pos = atomicAdd(&fill[d], 1);
  srcS[pos] = s;
  wS[pos] = dinv[s] * ew[e] * dinv[d];
}

// split fp32 array into bf16 hi/lo planes, 8 elems/thread (n % 8 == 0)
__global__ __launch_bounds__(256) void split_kernel(const float* __restrict__ in,
                                                    unsigned short* __restrict__ hi,
                                                    unsigned short* __restrict__ lo,
                                                    int n8) {
  int i = blockIdx.x * 256 + threadIdx.x;
  if (i >= n8) return;
  const float4 v0 = reinterpret_cast<const float4*>(in)[i * 2];
  const float4 v1 = reinterpret_cast<const float4*>(in)[i * 2 + 1];
  const float v[8] = {v0.x, v0.y, v0.z, v0.w, v1.x, v1.y, v1.z, v1.w};
  short8v h, l;
#pragma unroll
  for (int j = 0; j < 8; ++j) {
    unsigned short hh = f2bf(v[j]);
    h[j] = (short)hh;
    l[j] = (short)f2bf(v[j] - bf2f(hh));
  }
  reinterpret_cast<short8v*>(hi)[i] = h;
  reinterpret_cast<short8v*>(lo)[i] = l;
}

// W[K,N] -> transposed bf16 hi/lo planes [N][Kpad], zero-padded k>=K
__global__ __launch_bounds__(256) void wtrans_kernel(const float* __restrict__ W,
                                                     unsigned short* __restrict__ th,
                                                     unsigned short* __restrict__ tl,
                                                     int K, int N, int Kpad) {
  int idx = blockIdx.x * 256 + threadIdx.x;
  if (idx >= N * Kpad) return;
  int n = idx / Kpad, k = idx - n * Kpad;
  float v = (k < K) ? W[(size_t)k * N + n] : 0.f;
  unsigned short h = f2bf(v);
  th[idx] = h;
  tl[idx] = f2bf(v - bf2f(h));
}

// C[M,N] = A[M,KA] @ B[KA,N] from pre-split planes.
// Ah/Al: [M][KA] bf16 planes (KA % 8 == 0). BTh/BTl: [N][KB] transposed
// zero-padded planes (KB = KA rounded up to 32).
// 64x64 tile, BK=32, 4 waves (2x2), wave = 2x2 16x16 frags, 12 mfma/K-step.
template <bool BIAS, bool RELU, bool SPLIT>
__global__ __launch_bounds__(256) void gemm64_kernel(
    const unsigned short* __restrict__ Ah, const unsigned short* __restrict__ Al,
    const unsigned short* __restrict__ BTh, const unsigned short* __restrict__ BTl,
    const float* __restrict__ bias, float* __restrict__ Cf,
    unsigned short* __restrict__ Ch, unsigned short* __restrict__ Cl,
    int M, int KA, int KB, int N) {
  __shared__ unsigned short Ash[64][40];
  __shared__ unsigned short Asl[64][40];
  __shared__ unsigned short Bsh[64][40];
  __shared__ unsigned short Bsl[64][40];
  const int tid = threadIdx.x;
  const int lane = tid & 63;
  const int wid = tid >> 6;
  const int wm = wid >> 1, wn = wid & 1;  // 2x2 wave grid
  const int m0 = blockIdx.y * 64, n0 = blockIdx.x * 64;
  const int sr = tid >> 2, sko = (tid & 3) * 8;  // staging: row, k-offset
  const int arow = m0 + sr;
  const int brow = n0 + sr;
  const int l15 = lane & 15, kg = lane >> 4;
  const short8v zv = {0, 0, 0, 0, 0, 0, 0, 0};

  f32x4 acc[2][2];
#pragma unroll
  for (int i = 0; i < 2; ++i)
#pragma unroll
    for (int j = 0; j < 2; ++j)
#pragma unroll
      for (int c = 0; c < 4; ++c) acc[i][j][c] = 0.f;

  for (int k0 = 0; k0 < KB; k0 += 32) {
    // stage A: one b128 per plane per thread (guard K tail; KA % 8 == 0)
    short8v vah = zv, val = zv, vbh = zv, vbl = zv;
    if (arow < M && (k0 + sko) < KA) {
      const size_t off = (size_t)arow * KA + k0 + sko;
      vah = *reinterpret_cast<const short8v*>(Ah + off);
      val = *reinterpret_cast<const short8v*>(Al + off);
    }
    if (brow < N) {  // B planes are KB-padded: k always valid
      const size_t off = (size_t)brow * KB + k0 + sko;
      vbh = *reinterpret_cast<const short8v*>(BTh + off);
      vbl = *reinterpret_cast<const short8v*>(BTl + off);
    }
    *reinterpret_cast<short8v*>(&Ash[sr][sko]) = vah;
    *reinterpret_cast<short8v*>(&Asl[sr][sko]) = val;
    *reinterpret_cast<short8v*>(&Bsh[sr][sko]) = vbh;
    *reinterpret_cast<short8v*>(&Bsl[sr][sko]) = vbl;
    __syncthreads();
    short8v afh[2], afl[2], bfh[2], bfl[2];
#pragma unroll
    for (int mf = 0; mf < 2; ++mf) {
      const int r = wm * 32 + mf * 16 + l15;
      afh[mf] = *reinterpret_cast<const short8v*>(&Ash[r][kg * 8]);
      afl[mf] = *reinterpret_cast<const short8v*>(&Asl[r][kg * 8]);
    }
#pragma unroll
    for (int nf = 0; nf < 2; ++nf) {
      const int c = wn * 32 + nf * 16 + l15;
      bfh[nf] = *reinterpret_cast<const short8v*>(&Bsh[c][kg * 8]);
      bfl[nf] = *reinterpret_cast<const short8v*>(&Bsl[c][kg * 8]);
    }
#pragma unroll
    for (int mf = 0; mf < 2; ++mf)
#pragma unroll
      for (int nf = 0; nf < 2; ++nf) {
        acc[mf][nf] = __builtin_amdgcn_mfma_f32_16x16x32_bf16(afh[mf], bfh[nf], acc[mf][nf], 0, 0, 0);
        acc[mf][nf] = __builtin_amdgcn_mfma_f32_16x16x32_bf16(afh[mf], bfl[nf], acc[mf][nf], 0, 0, 0);
        acc[mf][nf] = __builtin_amdgcn_mfma_f32_16x16x32_bf16(afl[mf], bfh[nf], acc[mf][nf], 0, 0, 0);
      }
    __syncthreads();
  }

  // epilogue: C/D layout col=lane&15, row=(lane>>4)*4+reg (guide §3, m89/m91)
#pragma unroll
  for (int nf = 0; nf < 2; ++nf) {
    const int col = n0 + wn * 32 + nf * 16 + l15;
    if (col >= N) continue;
    float bb = 0.f;
    if (BIAS) bb = bias[col];
#pragma unroll
    for (int mf = 0; mf < 2; ++mf) {
      const int rbase = m0 + wm * 32 + mf * 16 + kg * 4;
#pragma unroll
      for (int i = 0; i < 4; ++i) {
        const int row = rbase + i;
        if (row >= M) continue;
        float v = acc[mf][nf][i];
        if (BIAS) v += bb;
        if (RELU) v = fmaxf(v, 0.f);
        if (SPLIT) {
          unsigned short h = f2bf(v);
          Ch[(size_t)row * N + col] = h;
          Cl[(size_t)row * N + col] = f2bf(v - bf2f(h));
        } else {
          Cf[(size_t)row * N + col] = v;
        }
      }
    }
  }
}

// Fused gather-aggregate + self-loop + bias + relu.
// NPW nodes/wave; F/4 lanes per node, ONE float4 per edge per lane.
// SPLIT: write bf16 hi/lo planes (feeds next GEMM); else fp32.
template <int F, int NPW, bool SPLIT>
__global__ __launch_bounds__(256) void agg_gather_kernel(const int* __restrict__ rowptr,
                                                         const int* __restrict__ srcS,
                                                         const float* __restrict__ wS,
                                                         const float* __restrict__ t,
                                                         const float* __restrict__ dinv,
                                                         const float* __restrict__ bias,
                                                         float* __restrict__ out,
                                                         unsigned short* __restrict__ oh,
                                                         unsigned short* __restrict__ ol) {
  constexpr int LPN = F / 4;  // float4 lanes per node
  const int wv = threadIdx.x >> 6;
  const int lane = threadIdx.x & 63;
  const int sub = (NPW == 2) ? (lane >> 5) : 0;
  const int l = (NPW == 2) ? (lane & 31) : lane;
  const int node = blockIdx.x * (4 * NPW) + wv * NPW + sub;
  if (node >= NN || l >= LPN) return;  // no barriers/shuffles below: safe exit
  const int beg = rowptr[node], end = rowptr[node + 1];
  const size_t fo = (size_t)l * 4;
  float4 acc0 = make_float4(0.f, 0.f, 0.f, 0.f);
  float4 acc1 = make_float4(0.f, 0.f, 0.f, 0.f);
  int j = beg;
  for (; j + 1 < end; j += 2) {  // 2-way unroll: independent load->FMA chains
    const int s0 = srcS[j], s1 = srcS[j + 1];
    const float w0 = wS[j], w1 = wS[j + 1];
    const float4 v0 = *reinterpret_cast<const float4*>(t + (size_t)s0 * F + fo);
    const float4 v1 = *reinterpret_cast<const float4*>(t + (size_t)s1 * F + fo);
    acc0.x = fmaf(v0.x, w0, acc0.x); acc0.y = fmaf(v0.y, w0, acc0.y);
    acc0.z = fmaf(v0.z, w0, acc0.z); acc0.w = fmaf(v0.w, w0, acc0.w);
    acc1.x = fmaf(v1.x, w1, acc1.x); acc1.y = fmaf(v1.y, w1, acc1.y);
    acc1.z = fmaf(v1.z, w1, acc1.z); acc1.w = fmaf(v1.w, w1, acc1.w);
  }
  if (j < end) {
    const int s0 = srcS[j];
    const float w0 = wS[j];
    const float4 v0 = *reinterpret_cast<const float4*>(t + (size_t)s0 * F + fo);
    acc0.x = fmaf(v0.x, w0, acc0.x); acc0.y = fmaf(v0.y, w0, acc0.y);
    acc0.z = fmaf(v0.z, w0, acc0.z); acc0.w = fmaf(v0.w, w0, acc0.w);
  }
  const float di = dinv[node];
  const float sw = di * di;
  const float4 tv = *reinterpret_cast<const float4*>(t + (size_t)node * F + fo);
  const float4 bb = *reinterpret_cast<const float4*>(bias + fo);
  float4 o;
  o.x = fmaxf(fmaf(tv.x, sw, acc0.x + acc1.x) + bb.x, 0.f);
  o.y = fmaxf(fmaf(tv.y, sw, acc0.y + acc1.y) + bb.y, 0.f);
  o.z = fmaxf(fmaf(tv.z, sw, acc0.z + acc1.z) + bb.z, 0.f);
  o.w = fmaxf(fmaf(tv.w, sw, acc0.w + acc1.w) + bb.w, 0.f);
  if (SPLIT) {
    ushort4 hv, lv;
    hv.x = f2bf(o.x); lv.x = f2bf(o.x - bf2f(hv.x));
    hv.y = f2bf(o.y); lv.y = f2bf(o.y - bf2f(hv.y));
    hv.z = f2bf(o.z); lv.z = f2bf(o.z - bf2f(hv.z));
    hv.w = f2bf(o.w); lv.w = f2bf(o.w - bf2f(hv.w));
    *reinterpret_cast<ushort4*>(oh + (size_t)node * F + fo) = hv;
    *reinterpret_cast<ushort4*>(ol + (size_t)node * F + fo) = lv;
  } else {
    *reinterpret_cast<float4*>(out + (size_t)node * F + fo) = o;
  }
}

extern "C" void kernel_launch(void* const* d_in, const int* in_sizes, int n_in,
                              void* d_out, int out_size, void* d_ws, size_t ws_size,
                              hipStream_t stream) {
  const float* x = (const float*)d_in[0];
  const int* ei = (const int*)d_in[1];  // int32 per harness conversion
  const float* ea = (const float*)d_in[2];
  const float* fcW = (const float*)d_in[3];
  const float* fcb = (const float*)d_in[4];
  const float* W1 = (const float*)d_in[5];
  const float* b1 = (const float*)d_in[6];
  const float* W2 = (const float*)d_in[7];
  const float* b2 = (const float*)d_in[8];
  const int* srcIdx = ei;       // edge_index[0]
  const int* dstIdx = ei + NE;  // edge_index[1]

  char* ws = (char*)d_ws;
  constexpr size_t KB_ = 1u << 10;
  typedef unsigned short us;
  float* dinv = (float*)(ws);                  // 80 KB
  int* rowptr = (int*)(ws + 128 * KB_);        // 80 KB
  int* cnt = (int*)(ws + 256 * KB_);           // 80 KB (count -> fill cursor)
  int* srcS = (int*)(ws + 384 * KB_);          // 1.28 MB
  float* wS = (float*)(ws + 1792 * KB_);       // 1.28 MB
  us* fcWTh = (us*)(ws + 3200 * KB_);          // 400x256 bf16 = 200 KB
  us* fcWTl = (us*)(ws + 3456 * KB_);
  us* W1Th = (us*)(ws + 3712 * KB_);           // 200x416 = 163 KB
  us* W1Tl = (us*)(ws + 3968 * KB_);
  us* W2Th = (us*)(ws + 4224 * KB_);           // 128x224 = 56 KB
  us* W2Tl = (us*)(ws + 4352 * KB_);
  us* xh = (us*)(ws + 4608 * KB_);             // 20000x256 = 9.77 MB
  us* xl = (us*)(ws + 14848 * KB_);            // ends ~24.3 MB
  float* t1 = (float*)(ws + 4608 * KB_);       // 15.26 MB (x dead) -> also t2
  us* h1h = (us*)(ws + 25600 * KB_);           // 20000x400 = 15.26 MB
  us* h1l = (us*)(ws + 41472 * KB_);           // ends ~55.8 MB (peak)
  us* h2h = (us*)(ws + 25600 * KB_);           // 7.63 MB (h1 dead)
  us* h2l = (us*)(ws + 33664 * KB_);
  float* t2 = (float*)(ws + 4608 * KB_);       // 9.77 MB (t1 dead)

  // --- normalization + CSR (shared by both GCN layers) ---
  hipMemsetAsync(dinv, 0, NN * sizeof(float), stream);
  hipMemsetAsync(cnt, 0, NN * sizeof(int), stream);
  deg_count_kernel<<<(NE + NN + 255) / 256, 256, 0, stream>>>(dstIdx, ea, dinv, cnt);
  dinv_kernel<<<(NN + 255) / 256, 256, 0, stream>>>(dinv);
  scan_kernel<<<1, 1024, 0, stream>>>(cnt, rowptr);
  scatter_kernel<<<(NE + 255) / 256, 256, 0, stream>>>(srcIdx, dstIdx, ea, dinv, cnt, srcS, wS);

  // --- one-time operand prep: split x, transpose+split weights ---
  split_kernel<<<(NN * IN_FT / 8 + 255) / 256, 256, 0, stream>>>(x, xh, xl, NN * IN_FT / 8);
  wtrans_kernel<<<(HID1 * IN_FT + 255) / 256, 256, 0, stream>>>(fcW, fcWTh, fcWTl, IN_FT, HID1, IN_FT);
  wtrans_kernel<<<(HID2 * K1P + 255) / 256, 256, 0, stream>>>(W1, W1Th, W1Tl, HID1, HID2, K1P);
  wtrans_kernel<<<(OUT_FT * K2P + 255) / 256, 256, 0, stream>>>(W2, W2Th, W2Tl, HID2, OUT_FT, K2P);

  const int MBLK = (NN + 63) / 64;  // 313 row blocks

  // --- h1 = relu(x @ fcW + fcb), written as bf16 hi/lo planes ---
  gemm64_kernel<true, true, true><<<dim3((HID1 + 63) / 64, MBLK), 256, 0, stream>>>(
      xh, xl, fcWTh, fcWTl, fcb, nullptr, h1h, h1l, NN, IN_FT, IN_FT, HID1);

  // --- layer 1: t1 = h1 @ W1 (fp32); h2 = relu(agg(t1)+..), split planes ---
  gemm64_kernel<false, false, false><<<dim3((HID2 + 63) / 64, MBLK), 256, 0, stream>>>(
      h1h, h1l, W1Th, W1Tl, nullptr, t1, nullptr, nullptr, NN, HID1, K1P, HID2);
  agg_gather_kernel<HID2, 1, true><<<(NN + 3) / 4, 256, 0, stream>>>(
      rowptr, srcS, wS, t1, dinv, b1, nullptr, h2h, h2l);

  // --- layer 2: t2 = h2 @ W2 (fp32); out = relu(agg(t2)+..) fp32 ---
  gemm64_kernel<false, false, false><<<dim3((OUT_FT + 63) / 64, MBLK), 256, 0, stream>>>(
      h2h, h2l, W2Th, W2Tl, nullptr, t2, nullptr, nullptr, NN, HID2, K2P, OUT_FT);
  agg_gather_kernel<OUT_FT, 2, false><<<(NN + 7) / 8, 256, 0, stream>>>(
      rowptr, srcS, wS, t2, dinv, b2, (float*)d_out, nullptr, nullptr);
}